// Round 10
// baseline (618.599 us; speedup 1.0000x reference)
//
#include <hip/hip_runtime.h>
#include <hip/hip_cooperative_groups.h>
#include <math.h>

namespace cg = cooperative_groups;

#define D 128
#define L 50
#define SCALE 0.08838834764831845f   // 1/sqrt(128)

using bf16x8 = __attribute__((ext_vector_type(8))) short;   // MFMA A/B frag
using f32x4  = __attribute__((ext_vector_type(4))) float;   // MFMA C/D frag

union FragU { bf16x8 f; uint2 u2[2]; uint4 u4; };

__device__ __forceinline__ unsigned f2bf(float x) {
    union { float f; unsigned u; } v; v.f = x;
    return (v.u + 0x7fffu + ((v.u >> 16) & 1u)) >> 16;
}
__device__ __forceinline__ float bflo(unsigned u) {
    union { unsigned u; float f; } v; v.u = u << 16; return v.f;
}
__device__ __forceinline__ float bfhi(unsigned u) {
    union { unsigned u; float f; } v; v.u = u & 0xffff0000u; return v.f;
}

struct AggShared {
    unsigned smail[2][L * 66];
    unsigned shb[2][64];
    float se2[2][2][64];
    float salpha[2][L], salpha1[2][L];
    int stime[2][L], sreorder[2][L], snbr[2][L], slast[2];
};
struct PrepShared { float T[2][128]; };
union SharedAll { AggShared agg; PrepShared prep; };

// ===========================================================================
// Shared phase bodies (used by both the mega kernel and fallback kernels).
// ===========================================================================
__device__ __forceinline__ void prep_body(
    int b, int t,
    const float* Wu, const float* Wi, const float* ue, const float* ie,
    const float* gu, const float* gi, const float* uu, const float* ui,
    const float* uek, const float* iek,
    unsigned* Bptu32, unsigned* Bpti32, unsigned* Btu32, unsigned* Bti32,
    float T[2][128])
{
    if (b < 50) {
        int side = b / 25;
        int o = (b % 25) * 256 + t;
        int d = o / L, l = o % L;
        const float* W = side ? Wi : Wu;
        const float* E = side ? ie : ue;
        unsigned short* Bpt = (unsigned short*)(side ? Bpti32 : Bptu32);
        float a = 0.f;
        for (int k = 0; k < D; ++k) a += W[d * D + k] * E[l * D + k];
        Bpt[(128 + l) * 128 + d] = (unsigned short)f2bf(a);
    } else if (b < 306) {
        int bb = b - 50;
        int side = bb / 128;
        int o = (bb % 128) * 256 + t;
        int r = o >> 7, c = o & 127;                // r 0..255 (GU rows)
        const float* G = side ? gi : gu;
        const float* U = side ? ui : uu;
        unsigned short* Bt = (unsigned short*)(side ? Bti32 : Btu32);
        float a = 0.f;
        for (int k = 0; k < D; ++k) a += G[r * D + k] * U[k * D + c];
        Bt[c * 448 + r] = (unsigned short)f2bf(a);
    } else if (b < 434) {
        int bb = b - 306;
        int side = bb >> 6;
        int o = (bb & 63) * 256 + t;
        int r = o >> 7, c = o & 127;                // r 0..127 (upd_bot)
        const float* U = side ? ui : uu;
        unsigned short* Bt = (unsigned short*)(side ? Bti32 : Btu32);
        Bt[c * 448 + 320 + r] = (unsigned short)f2bf(U[(128 + r) * D + c]);
        if (r < 14) Bt[c * 448 + 306 + r] = 0;
    } else if (b < 562) {
        int bb = b - 434;
        int side = bb >> 6;
        int o = (bb & 63) * 256 + t;
        int k = o >> 7, c = o & 127;
        const float* W = side ? Wi : Wu;
        unsigned short* Bpt = (unsigned short*)(side ? Bpti32 : Bptu32);
        Bpt[c * 128 + k] = (unsigned short)f2bf(W[k * D + c]);
    } else if (b < 564) {
        int side = b - 562;
        unsigned short* Bpt = (unsigned short*)(side ? Bpti32 : Bptu32);
        for (int j = 0; j < 7; ++j)
            Bpt[178 * 128 + t * 7 + j] = 0;
    } else {
        int bb = b - 564;
        int side = bb / 25;
        int ro = (bb % 25) * 2;
        const float* EK = side ? iek : uek;
        const float* G  = side ? gi : gu;
        const float* U  = side ? ui : uu;
        unsigned short* Bt = (unsigned short*)(side ? Bti32 : Btu32);
        int r = t >> 7, c = t & 127;
        float a = 0.f;
        for (int k = 0; k < D; ++k) a += EK[(ro + r) * D + k] * G[k * D + c];
        T[r][c] = a;
        __syncthreads();
        float e = 0.f;
        for (int j = 0; j < D; ++j) e += T[r][j] * U[j * D + c];
        Bt[c * 448 + 256 + ro + r] = (unsigned short)f2bf(e);
        __syncthreads();
    }
}

__device__ __forceinline__ void proj_body(
    int w, int t, const float* user, const float* item,
    const unsigned* Bptu32, const unsigned* Bpti32,
    unsigned* h32, float* eproj, unsigned* A32, int NU)
{
    int wave = t >> 6, lane = t & 63;
    int m16 = lane & 15, quad = lane >> 4;
    int nb = w * 16;
    const float* X = (nb < NU) ? user : item;
    int xoff = (nb < NU) ? 0 : NU;
    const unsigned* Bt = (nb < NU) ? Bptu32 : Bpti32;   // [192][64 u32]

    f32x4 acc[3] = {{0.f,0.f,0.f,0.f},{0.f,0.f,0.f,0.f},{0.f,0.f,0.f,0.f}};
    #pragma unroll
    for (int kc = 0; kc < 4; ++kc) {
        int row = nb + m16;
        const float* src = &X[(size_t)(row - xoff) * D + kc * 32 + quad * 8];
        float4 v0 = *(const float4*)&src[0];
        float4 v1 = *(const float4*)&src[4];
        FragU a;
        a.u4.x = f2bf(v0.x) | (f2bf(v0.y) << 16);
        a.u4.y = f2bf(v0.z) | (f2bf(v0.w) << 16);
        a.u4.z = f2bf(v1.x) | (f2bf(v1.y) << 16);
        a.u4.w = f2bf(v1.z) | (f2bf(v1.w) << 16);
        if (wave == 0)
            *(uint4*)&A32[(size_t)row * 224 + 160 + kc * 16 + quad * 4] = a.u4;
        #pragma unroll
        for (int ni = 0; ni < 3; ++ni) {
            int c = wave * 48 + ni * 16 + m16;
            FragU bb;
            bb.u4 = *(const uint4*)&Bt[(size_t)c * 64 + kc * 16 + quad * 4];
            acc[ni] = __builtin_amdgcn_mfma_f32_16x16x32_bf16(a.f, bb.f, acc[ni], 0, 0, 0);
        }
    }
    #pragma unroll
    for (int ni = 0; ni < 3; ++ni) {
        int col = wave * 48 + ni * 16 + m16;
        #pragma unroll
        for (int r = 0; r < 4; ++r) {
            float me = acc[ni][r];
            float pr = __shfl_xor(me, 1);
            int row = nb + quad * 4 + r;
            if (col < 128) {
                if (!(lane & 1))
                    h32[(size_t)row * 64 + (col >> 1)] = f2bf(me) | (f2bf(pr) << 16);
            } else if (col < 178) {
                eproj[(size_t)row * L + (col - 128)] = me;
            }
        }
    }
}

__device__ __forceinline__ void agg_body(
    int w, int tb, AggShared& sh,
    const unsigned* h32, const float* eproj,
    const int* unbr, const int* untime, const int* inbr, const int* intime,
    unsigned* A32, int NU)
{
    int sub = tb >> 7;
    int ta = tb & 127;
    int awave = ta >> 6, alane = ta & 63;
    int am16 = alane & 15, aquad = alane >> 4;
    int g = w * 2 + sub;

    const unsigned* mail; const int* nbrp; const int* timp;
    if (g < NU) { mail = h32 + (size_t)NU * 64; nbrp = unbr + (size_t)g * L;        timp = untime + (size_t)g * L; }
    else        { mail = h32;                   nbrp = inbr + (size_t)(g - NU) * L; timp = intime + (size_t)(g - NU) * L; }

    if (ta < 64) sh.shb[sub][ta] = h32[(size_t)g * 64 + ta];
    if (ta < L) { sh.stime[sub][ta] = timp[ta]; sh.snbr[sub][ta] = nbrp[ta]; }
    __syncthreads();

    if (ta < L) {
        int ti = sh.stime[sub][ta]; int rank = 0; bool firstmax = true;
        for (int j = 0; j < L; ++j) {
            int tj = sh.stime[sub][j];
            rank += (tj < ti) || (tj == ti && j < ta);
            firstmax = firstmax && ((tj < ti) || (tj == ti && j >= ta));
        }
        sh.sreorder[sub][ta] = L - 1 - rank;
        if (firstmax) sh.slast[sub] = ta;
    }
    {
        int q = ta >> 5, p = ta & 31;
        #pragma unroll
        for (int i = 0; i < 13; ++i) {
            int l = i * 4 + q;
            if (l < L) {
                uint2 v = *(const uint2*)&mail[(size_t)sh.snbr[sub][l] * 64 + p * 2];
                *(uint2*)&sh.smail[sub][l * 66 + 2 * p] = v;
            }
        }
    }
    __syncthreads();

    {
        const unsigned* bptr = (am16 == 1) ? &sh.smail[sub][sh.slast[sub] * 66]
                                           : &sh.shb[sub][0];
        int s0 = awave * 32 + am16;       if (s0 > 49) s0 = 49;
        int s1 = awave * 32 + 16 + am16;  if (s1 > 49) s1 = 49;
        const unsigned* a0p = &sh.smail[sub][s0 * 66];
        const unsigned* a1p = &sh.smail[sub][s1 * 66];
        f32x4 d0 = {0.f, 0.f, 0.f, 0.f}, d1 = {0.f, 0.f, 0.f, 0.f};
        #pragma unroll
        for (int kc = 0; kc < 4; ++kc) {
            int off = kc * 16 + aquad * 4;
            FragU bf_, af0, af1;
            bf_.u2[0] = *(const uint2*)&bptr[off];
            bf_.u2[1] = *(const uint2*)&bptr[off + 2];
            af0.u2[0] = *(const uint2*)&a0p[off];
            af0.u2[1] = *(const uint2*)&a0p[off + 2];
            af1.u2[0] = *(const uint2*)&a1p[off];
            af1.u2[1] = *(const uint2*)&a1p[off + 2];
            d0 = __builtin_amdgcn_mfma_f32_16x16x32_bf16(af0.f, bf_.f, d0, 0, 0, 0);
            d1 = __builtin_amdgcn_mfma_f32_16x16x32_bf16(af1.f, bf_.f, d1, 0, 0, 0);
        }
        if (am16 < 2) {
            #pragma unroll
            for (int r = 0; r < 4; ++r) {
                sh.se2[sub][am16][awave * 32 + aquad * 4 + r]      = d0[r];
                sh.se2[sub][am16][awave * 32 + 16 + aquad * 4 + r] = d1[r];
            }
        }
    }
    __syncthreads();

    float sc = -1e30f;
    if (alane < L) {
        sc = (awave == 0)
           ? (sh.se2[sub][0][alane] + eproj[(size_t)g * L + sh.sreorder[sub][alane]]) * SCALE
           : sh.se2[sub][1][alane] * SCALE;
    }
    float mx = sc;
    for (int off = 32; off; off >>= 1) mx = fmaxf(mx, __shfl_xor(mx, off));
    float ex = (alane < L) ? expf(sc - mx) : 0.f;
    float smv = ex;
    for (int off = 32; off; off >>= 1) smv += __shfl_xor(smv, off);
    float al = ex / smv;
    if (alane < L) {
        if (awave == 0) sh.salpha[sub][alane] = al;
        else            sh.salpha1[sub][alane] = al;
    }
    __syncthreads();

    {
        const float* alp = awave ? sh.salpha1[sub] : sh.salpha[sub];
        const unsigned* base = &sh.smail[sub][alane];
        float ax = 0.f, ay = 0.f;
        for (int l = 0; l < L; ++l) {
            unsigned u = base[l * 66];
            float a = alp[l];
            ax += a * bflo(u);
            ay += a * bfhi(u);
        }
        A32[(size_t)g * 224 + awave * 64 + alane] = f2bf(ax) | (f2bf(ay) << 16);
    }
    if (ta >= 64 && ta < 96) A32[(size_t)g * 224 + 128 + (ta - 64)] = 0u;
    __syncthreads();
    if (ta < L) {
        ((unsigned short*)A32)[(size_t)g * 448 + 256 + sh.sreorder[sub][ta]] =
            (unsigned short)f2bf(sh.salpha[sub][ta]);
    }
    __syncthreads();
}

__device__ __forceinline__ void gemm_body(
    int w, int t, const unsigned* A32,
    const unsigned* Btu32, const unsigned* Bti32, float* out, int NU)
{
    int wave = t >> 6, lane = t & 63;
    int m16 = lane & 15, quad = lane >> 4;
    int rowblk = w >> 1, half = w & 1;
    int nb = rowblk * 128;
    const unsigned* Bt = (nb < NU) ? Btu32 : Bti32;     // [128 n][224 u32]
    int mr0 = nb + (wave * 2) * 16 + m16;
    int mr1 = mr0 + 16;

    f32x4 acc[2][4];
    #pragma unroll
    for (int i = 0; i < 2; ++i)
        #pragma unroll
        for (int j = 0; j < 4; ++j) acc[i][j] = (f32x4){0.f, 0.f, 0.f, 0.f};

    for (int kc = 0; kc < 14; ++kc) {
        FragU a0, a1;
        a0.u4 = *(const uint4*)&A32[(size_t)mr0 * 224 + kc * 16 + quad * 4];
        a1.u4 = *(const uint4*)&A32[(size_t)mr1 * 224 + kc * 16 + quad * 4];
        #pragma unroll
        for (int ni = 0; ni < 4; ++ni) {
            FragU bf;
            bf.u4 = *(const uint4*)&Bt[(size_t)(half * 64 + ni * 16 + m16) * 224 + kc * 16 + quad * 4];
            acc[0][ni] = __builtin_amdgcn_mfma_f32_16x16x32_bf16(a0.f, bf.f, acc[0][ni], 0, 0, 0);
            acc[1][ni] = __builtin_amdgcn_mfma_f32_16x16x32_bf16(a1.f, bf.f, acc[1][ni], 0, 0, 0);
        }
    }
    #pragma unroll
    for (int j = 0; j < 2; ++j) {
        int mrow0 = nb + (wave * 2 + j) * 16;
        #pragma unroll
        for (int ni = 0; ni < 4; ++ni)
            #pragma unroll
            for (int r = 0; r < 4; ++r) {
                int row = mrow0 + quad * 4 + r;
                int col = half * 64 + ni * 16 + m16;
                out[(size_t)row * D + col] = tanhf(acc[j][ni][r]);
            }
    }
}

// ===========================================================================
// Mega kernel: all 4 phases with grid.sync between them (cooperative launch).
// ===========================================================================
__global__ __launch_bounds__(256, 2) void mega_kernel(
    const float* __restrict__ user, const float* __restrict__ item,
    const float* __restrict__ Wu, const float* __restrict__ Wi,
    const float* __restrict__ gu, const float* __restrict__ gi,
    const float* __restrict__ uu, const float* __restrict__ ui,
    const float* __restrict__ ue, const float* __restrict__ ie,
    const float* __restrict__ uek, const float* __restrict__ iek,
    const int* __restrict__ unbr, const int* __restrict__ untime,
    const int* __restrict__ inbr, const int* __restrict__ intime,
    float* __restrict__ eproj, unsigned* __restrict__ h32,
    unsigned* __restrict__ A32,
    unsigned* __restrict__ Btu32, unsigned* __restrict__ Bti32,
    unsigned* __restrict__ Bptu32, unsigned* __restrict__ Bpti32,
    float* __restrict__ out, int NU, int NI)
{
    __shared__ SharedAll sm;
    cg::grid_group grid = cg::this_grid();
    int t = threadIdx.x;
    int N = NU + NI;

    for (int b = blockIdx.x; b < 614; b += gridDim.x)
        prep_body(b, t, Wu, Wi, ue, ie, gu, gi, uu, ui, uek, iek,
                  Bptu32, Bpti32, Btu32, Bti32, sm.prep.T);
    __threadfence();
    grid.sync();

    for (int w = blockIdx.x; w < N / 16; w += gridDim.x)
        proj_body(w, t, user, item, Bptu32, Bpti32, h32, eproj, A32, NU);
    __threadfence();
    grid.sync();

    for (int w = blockIdx.x; w < N / 2; w += gridDim.x)
        agg_body(w, t, sm.agg, h32, eproj, unbr, untime, inbr, intime, A32, NU);
    __threadfence();
    grid.sync();

    for (int w = blockIdx.x; w < N / 64; w += gridDim.x)
        gemm_body(w, t, A32, Btu32, Bti32, out, NU);
}

// ===========================================================================
// Fallback kernels (R8 pipeline, via the same bodies).
// ===========================================================================
__global__ __launch_bounds__(256) void prep_k(
    const float* Wu, const float* Wi, const float* ue, const float* ie,
    const float* gu, const float* gi, const float* uu, const float* ui,
    const float* uek, const float* iek,
    unsigned* Bptu32, unsigned* Bpti32, unsigned* Btu32, unsigned* Bti32)
{
    __shared__ float T[2][128];
    prep_body(blockIdx.x, threadIdx.x, Wu, Wi, ue, ie, gu, gi, uu, ui,
              uek, iek, Bptu32, Bpti32, Btu32, Bti32, T);
}

__global__ __launch_bounds__(256) void proj_k(
    const float* user, const float* item,
    const unsigned* Bptu32, const unsigned* Bpti32,
    unsigned* h32, float* eproj, unsigned* A32, int NU)
{
    proj_body(blockIdx.x, threadIdx.x, user, item, Bptu32, Bpti32,
              h32, eproj, A32, NU);
}

__global__ __launch_bounds__(256) void agg_k(
    const unsigned* h32, const float* eproj,
    const int* unbr, const int* untime, const int* inbr, const int* intime,
    unsigned* A32, int NU)
{
    __shared__ AggShared sh;
    agg_body(blockIdx.x, threadIdx.x, sh, h32, eproj, unbr, untime,
             inbr, intime, A32, NU);
}

__global__ __launch_bounds__(256) void gemm_k(
    const unsigned* A32, const unsigned* Btu32, const unsigned* Bti32,
    float* out, int NU)
{
    gemm_body(blockIdx.x, threadIdx.x, A32, Btu32, Bti32, out, NU);
}

// ===========================================================================
extern "C" void kernel_launch(void* const* d_in, const int* in_sizes, int n_in,
                              void* d_out, int out_size, void* d_ws, size_t ws_size,
                              hipStream_t stream) {
    const float* user   = (const float*)d_in[0];
    const float* item   = (const float*)d_in[1];
    const float* Wu     = (const float*)d_in[2];
    const float* Wi     = (const float*)d_in[3];
    const float* gate_u = (const float*)d_in[4];
    const float* gate_i = (const float*)d_in[5];
    const float* upd_u  = (const float*)d_in[6];
    const float* upd_i  = (const float*)d_in[7];
    const float* uemb   = (const float*)d_in[8];
    const float* uembk  = (const float*)d_in[9];
    const float* iemb   = (const float*)d_in[10];
    const float* iembk  = (const float*)d_in[11];
    const int*   unbr   = (const int*)d_in[12];
    const int*   untime = (const int*)d_in[13];
    const int*   inbr   = (const int*)d_in[14];
    const int*   intime = (const int*)d_in[15];

    int NU = in_sizes[0] / D;
    int NI = in_sizes[1] / D;
    int N  = NU + NI;

    float* eproj  = (float*)d_ws;                   // N*50 f32
    unsigned* h32   = (unsigned*)(eproj + (size_t)N * L);  // N*64 u32
    unsigned* A32   = h32 + (size_t)N * 64;         // N*224 u32
    unsigned* Btu32 = A32 + (size_t)N * 224;        // 128*224 u32 each
    unsigned* Bti32 = Btu32 + 128 * 224;
    unsigned* Bptu32 = Bti32 + 128 * 224;           // 192*64 u32 each
    unsigned* Bpti32 = Bptu32 + 192 * 64;
    float* out = (float*)d_out;

    // --- cooperative attempt: runtime-validated grid size -----------------
    hipError_t rc = hipErrorUnknown;
    int coop = 0, numCU = 0, maxBlk = 0, dev = 0;
    (void)hipGetDevice(&dev);
    (void)hipDeviceGetAttribute(&coop, hipDeviceAttributeCooperativeLaunch, dev);
    (void)hipDeviceGetAttribute(&numCU, hipDeviceAttributeMultiprocessorCount, dev);
    (void)hipOccupancyMaxActiveBlocksPerMultiprocessor(
        &maxBlk, (const void*)mega_kernel, 256, 0);
    if (coop && numCU > 0 && maxBlk > 0) {
        int nblk = maxBlk * numCU;
        if (nblk > 768) nblk = 768;
        void* args[] = {
            (void*)&user, (void*)&item, (void*)&Wu, (void*)&Wi,
            (void*)&gate_u, (void*)&gate_i, (void*)&upd_u, (void*)&upd_i,
            (void*)&uemb, (void*)&iemb, (void*)&uembk, (void*)&iembk,
            (void*)&unbr, (void*)&untime, (void*)&inbr, (void*)&intime,
            (void*)&eproj, (void*)&h32, (void*)&A32,
            (void*)&Btu32, (void*)&Bti32, (void*)&Bptu32, (void*)&Bpti32,
            (void*)&out, (void*)&NU, (void*)&NI
        };
        rc = hipLaunchCooperativeKernel((void*)mega_kernel, dim3(nblk),
                                        dim3(256), args, 0, stream);
    }
    // --- fallback: proven 4-kernel pipeline -------------------------------
    if (rc != hipSuccess) {
        prep_k<<<614, 256, 0, stream>>>(Wu, Wi, uemb, iemb, gate_u, gate_i,
                                        upd_u, upd_i, uembk, iembk,
                                        Bptu32, Bpti32, Btu32, Bti32);
        proj_k<<<N / 16, 256, 0, stream>>>(user, item, Bptu32, Bpti32,
                                           h32, eproj, A32, NU);
        agg_k<<<N / 2, 256, 0, stream>>>(h32, eproj, unbr, untime, inbr,
                                         intime, A32, NU);
        gemm_k<<<N / 64, 256, 0, stream>>>(A32, Btu32, Bti32, out, NU);
    }
}

// Round 11
// 543.027 us; speedup vs baseline: 1.1392x; 1.1392x over previous
//
#include <hip/hip_runtime.h>
#include <math.h>

#define D 128
#define L 50
#define SCALE 0.08838834764831845f   // 1/sqrt(128)

using bf16x8 = __attribute__((ext_vector_type(8))) short;   // MFMA A/B frag
using f32x4  = __attribute__((ext_vector_type(4))) float;   // MFMA C/D frag

union FragU { bf16x8 f; uint2 u2[2]; uint4 u4; };

__device__ __forceinline__ unsigned f2bf(float x) {
    union { float f; unsigned u; } v; v.f = x;
    return (v.u + 0x7fffu + ((v.u >> 16) & 1u)) >> 16;
}
__device__ __forceinline__ float bflo(unsigned u) {
    union { unsigned u; float f; } v; v.u = u << 16; return v.f;
}
__device__ __forceinline__ float bfhi(unsigned u) {
    union { unsigned u; float f; } v; v.u = u & 0xffff0000u; return v.f;
}

struct AggShared {
    unsigned smail[2][L * 66];
    unsigned shb[2][64];
    float se2[2][2][64];
    float salpha[2][L], salpha1[2][L];
    int stime[2][L], sreorder[2][L], snbr[2][L], slast[2];
};
struct PrepShared { float T[2][128]; };
union SharedAll { AggShared agg; PrepShared prep; };

// ---- lightweight grid barrier (counters zeroed by hipMemsetAsync) ---------
__device__ __forceinline__ void grid_barrier(unsigned* cnt, int idx) {
    __syncthreads();
    __threadfence();                                  // release (agent scope)
    if (threadIdx.x == 0) {
        __hip_atomic_fetch_add(&cnt[idx * 16], 1u, __ATOMIC_ACQ_REL,
                               __HIP_MEMORY_SCOPE_AGENT);
        while (__hip_atomic_load(&cnt[idx * 16], __ATOMIC_ACQUIRE,
                                 __HIP_MEMORY_SCOPE_AGENT) < gridDim.x)
            __builtin_amdgcn_s_sleep(2);
    }
    __syncthreads();
    __threadfence();                                  // acquire (L1 refresh)
}

// ===========================================================================
// Shared phase bodies (mega + fallback kernels).
// ===========================================================================
__device__ __forceinline__ void prep_body(
    int b, int t,
    const float* Wu, const float* Wi, const float* ue, const float* ie,
    const float* gu, const float* gi, const float* uu, const float* ui,
    const float* uek, const float* iek,
    unsigned* Bptu32, unsigned* Bpti32, unsigned* Btu32, unsigned* Bti32,
    float T[2][128])
{
    if (b < 50) {
        int side = b / 25;
        int o = (b % 25) * 256 + t;
        int d = o / L, l = o % L;
        const float* W = side ? Wi : Wu;
        const float* E = side ? ie : ue;
        unsigned short* Bpt = (unsigned short*)(side ? Bpti32 : Bptu32);
        float a = 0.f;
        for (int k = 0; k < D; ++k) a += W[d * D + k] * E[l * D + k];
        Bpt[(128 + l) * 128 + d] = (unsigned short)f2bf(a);
    } else if (b < 306) {
        int bb = b - 50;
        int side = bb / 128;
        int o = (bb % 128) * 256 + t;
        int r = o >> 7, c = o & 127;                // r 0..255 (GU rows)
        const float* G = side ? gi : gu;
        const float* U = side ? ui : uu;
        unsigned short* Bt = (unsigned short*)(side ? Bti32 : Btu32);
        float a = 0.f;
        for (int k = 0; k < D; ++k) a += G[r * D + k] * U[k * D + c];
        Bt[c * 448 + r] = (unsigned short)f2bf(a);
    } else if (b < 434) {
        int bb = b - 306;
        int side = bb >> 6;
        int o = (bb & 63) * 256 + t;
        int r = o >> 7, c = o & 127;                // r 0..127 (upd_bot)
        const float* U = side ? ui : uu;
        unsigned short* Bt = (unsigned short*)(side ? Bti32 : Btu32);
        Bt[c * 448 + 320 + r] = (unsigned short)f2bf(U[(128 + r) * D + c]);
        if (r < 14) Bt[c * 448 + 306 + r] = 0;
    } else if (b < 562) {
        int bb = b - 434;
        int side = bb >> 6;
        int o = (bb & 63) * 256 + t;
        int k = o >> 7, c = o & 127;
        const float* W = side ? Wi : Wu;
        unsigned short* Bpt = (unsigned short*)(side ? Bpti32 : Bptu32);
        Bpt[c * 128 + k] = (unsigned short)f2bf(W[k * D + c]);
    } else if (b < 564) {
        int side = b - 562;
        unsigned short* Bpt = (unsigned short*)(side ? Bpti32 : Bptu32);
        for (int j = 0; j < 7; ++j)
            Bpt[178 * 128 + t * 7 + j] = 0;
    } else {
        int bb = b - 564;
        int side = bb / 25;
        int ro = (bb % 25) * 2;
        const float* EK = side ? iek : uek;
        const float* G  = side ? gi : gu;
        const float* U  = side ? ui : uu;
        unsigned short* Bt = (unsigned short*)(side ? Bti32 : Btu32);
        int r = t >> 7, c = t & 127;
        float a = 0.f;
        for (int k = 0; k < D; ++k) a += EK[(ro + r) * D + k] * G[k * D + c];
        T[r][c] = a;
        __syncthreads();
        float e = 0.f;
        for (int j = 0; j < D; ++j) e += T[r][j] * U[j * D + c];
        Bt[c * 448 + 256 + ro + r] = (unsigned short)f2bf(e);
        __syncthreads();
    }
}

__device__ __forceinline__ void proj_body(
    int w, int t, const float* user, const float* item,
    const unsigned* Bptu32, const unsigned* Bpti32,
    unsigned* h32, float* eproj, unsigned* A32, int NU)
{
    int wave = t >> 6, lane = t & 63;
    int m16 = lane & 15, quad = lane >> 4;
    int nb = w * 16;
    const float* X = (nb < NU) ? user : item;
    int xoff = (nb < NU) ? 0 : NU;
    const unsigned* Bt = (nb < NU) ? Bptu32 : Bpti32;   // [192][64 u32]

    f32x4 acc[3] = {{0.f,0.f,0.f,0.f},{0.f,0.f,0.f,0.f},{0.f,0.f,0.f,0.f}};
    #pragma unroll
    for (int kc = 0; kc < 4; ++kc) {
        int row = nb + m16;
        const float* src = &X[(size_t)(row - xoff) * D + kc * 32 + quad * 8];
        float4 v0 = *(const float4*)&src[0];
        float4 v1 = *(const float4*)&src[4];
        FragU a;
        a.u4.x = f2bf(v0.x) | (f2bf(v0.y) << 16);
        a.u4.y = f2bf(v0.z) | (f2bf(v0.w) << 16);
        a.u4.z = f2bf(v1.x) | (f2bf(v1.y) << 16);
        a.u4.w = f2bf(v1.z) | (f2bf(v1.w) << 16);
        if (wave == 0)
            *(uint4*)&A32[(size_t)row * 224 + 160 + kc * 16 + quad * 4] = a.u4;
        #pragma unroll
        for (int ni = 0; ni < 3; ++ni) {
            int c = wave * 48 + ni * 16 + m16;
            FragU bb;
            bb.u4 = *(const uint4*)&Bt[(size_t)c * 64 + kc * 16 + quad * 4];
            acc[ni] = __builtin_amdgcn_mfma_f32_16x16x32_bf16(a.f, bb.f, acc[ni], 0, 0, 0);
        }
    }
    #pragma unroll
    for (int ni = 0; ni < 3; ++ni) {
        int col = wave * 48 + ni * 16 + m16;
        #pragma unroll
        for (int r = 0; r < 4; ++r) {
            float me = acc[ni][r];
            float pr = __shfl_xor(me, 1);
            int row = nb + quad * 4 + r;
            if (col < 128) {
                if (!(lane & 1))
                    h32[(size_t)row * 64 + (col >> 1)] = f2bf(me) | (f2bf(pr) << 16);
            } else if (col < 178) {
                eproj[(size_t)row * L + (col - 128)] = me;
            }
        }
    }
}

__device__ __forceinline__ void agg_body(
    int w, int tb, AggShared& sh,
    const unsigned* h32, const float* eproj,
    const int* unbr, const int* untime, const int* inbr, const int* intime,
    unsigned* A32, int NU)
{
    int sub = tb >> 7;
    int ta = tb & 127;
    int awave = ta >> 6, alane = ta & 63;
    int am16 = alane & 15, aquad = alane >> 4;
    int g = w * 2 + sub;

    const unsigned* mail; const int* nbrp; const int* timp;
    if (g < NU) { mail = h32 + (size_t)NU * 64; nbrp = unbr + (size_t)g * L;        timp = untime + (size_t)g * L; }
    else        { mail = h32;                   nbrp = inbr + (size_t)(g - NU) * L; timp = intime + (size_t)(g - NU) * L; }

    if (ta < 64) sh.shb[sub][ta] = h32[(size_t)g * 64 + ta];
    if (ta < L) { sh.stime[sub][ta] = timp[ta]; sh.snbr[sub][ta] = nbrp[ta]; }
    __syncthreads();

    if (ta < L) {
        int ti = sh.stime[sub][ta]; int rank = 0; bool firstmax = true;
        for (int j = 0; j < L; ++j) {
            int tj = sh.stime[sub][j];
            rank += (tj < ti) || (tj == ti && j < ta);
            firstmax = firstmax && ((tj < ti) || (tj == ti && j >= ta));
        }
        sh.sreorder[sub][ta] = L - 1 - rank;
        if (firstmax) sh.slast[sub] = ta;
    }
    {
        int q = ta >> 5, p = ta & 31;
        #pragma unroll
        for (int i = 0; i < 13; ++i) {
            int l = i * 4 + q;
            if (l < L) {
                uint2 v = *(const uint2*)&mail[(size_t)sh.snbr[sub][l] * 64 + p * 2];
                *(uint2*)&sh.smail[sub][l * 66 + 2 * p] = v;
            }
        }
    }
    __syncthreads();

    {
        const unsigned* bptr = (am16 == 1) ? &sh.smail[sub][sh.slast[sub] * 66]
                                           : &sh.shb[sub][0];
        int s0 = awave * 32 + am16;       if (s0 > 49) s0 = 49;
        int s1 = awave * 32 + 16 + am16;  if (s1 > 49) s1 = 49;
        const unsigned* a0p = &sh.smail[sub][s0 * 66];
        const unsigned* a1p = &sh.smail[sub][s1 * 66];
        f32x4 d0 = {0.f, 0.f, 0.f, 0.f}, d1 = {0.f, 0.f, 0.f, 0.f};
        #pragma unroll
        for (int kc = 0; kc < 4; ++kc) {
            int off = kc * 16 + aquad * 4;
            FragU bf_, af0, af1;
            bf_.u2[0] = *(const uint2*)&bptr[off];
            bf_.u2[1] = *(const uint2*)&bptr[off + 2];
            af0.u2[0] = *(const uint2*)&a0p[off];
            af0.u2[1] = *(const uint2*)&a0p[off + 2];
            af1.u2[0] = *(const uint2*)&a1p[off];
            af1.u2[1] = *(const uint2*)&a1p[off + 2];
            d0 = __builtin_amdgcn_mfma_f32_16x16x32_bf16(af0.f, bf_.f, d0, 0, 0, 0);
            d1 = __builtin_amdgcn_mfma_f32_16x16x32_bf16(af1.f, bf_.f, d1, 0, 0, 0);
        }
        if (am16 < 2) {
            #pragma unroll
            for (int r = 0; r < 4; ++r) {
                sh.se2[sub][am16][awave * 32 + aquad * 4 + r]      = d0[r];
                sh.se2[sub][am16][awave * 32 + 16 + aquad * 4 + r] = d1[r];
            }
        }
    }
    __syncthreads();

    float sc = -1e30f;
    if (alane < L) {
        sc = (awave == 0)
           ? (sh.se2[sub][0][alane] + eproj[(size_t)g * L + sh.sreorder[sub][alane]]) * SCALE
           : sh.se2[sub][1][alane] * SCALE;
    }
    float mx = sc;
    for (int off = 32; off; off >>= 1) mx = fmaxf(mx, __shfl_xor(mx, off));
    float ex = (alane < L) ? expf(sc - mx) : 0.f;
    float smv = ex;
    for (int off = 32; off; off >>= 1) smv += __shfl_xor(smv, off);
    float al = ex / smv;
    if (alane < L) {
        if (awave == 0) sh.salpha[sub][alane] = al;
        else            sh.salpha1[sub][alane] = al;
    }
    __syncthreads();

    {
        const float* alp = awave ? sh.salpha1[sub] : sh.salpha[sub];
        const unsigned* base = &sh.smail[sub][alane];
        float ax = 0.f, ay = 0.f;
        for (int l = 0; l < L; ++l) {
            unsigned u = base[l * 66];
            float a = alp[l];
            ax += a * bflo(u);
            ay += a * bfhi(u);
        }
        A32[(size_t)g * 224 + awave * 64 + alane] = f2bf(ax) | (f2bf(ay) << 16);
    }
    if (ta >= 64 && ta < 96) A32[(size_t)g * 224 + 128 + (ta - 64)] = 0u;
    __syncthreads();
    if (ta < L) {
        ((unsigned short*)A32)[(size_t)g * 448 + 256 + sh.sreorder[sub][ta]] =
            (unsigned short)f2bf(sh.salpha[sub][ta]);
    }
    __syncthreads();
}

__device__ __forceinline__ void gemm_body(
    int w, int t, const unsigned* A32,
    const unsigned* Btu32, const unsigned* Bti32, float* out, int NU)
{
    int wave = t >> 6, lane = t & 63;
    int m16 = lane & 15, quad = lane >> 4;
    int rowblk = w >> 1, half = w & 1;
    int nb = rowblk * 128;
    const unsigned* Bt = (nb < NU) ? Btu32 : Bti32;     // [128 n][224 u32]
    int mr0 = nb + (wave * 2) * 16 + m16;
    int mr1 = mr0 + 16;

    f32x4 acc[2][4];
    #pragma unroll
    for (int i = 0; i < 2; ++i)
        #pragma unroll
        for (int j = 0; j < 4; ++j) acc[i][j] = (f32x4){0.f, 0.f, 0.f, 0.f};

    for (int kc = 0; kc < 14; ++kc) {
        FragU a0, a1;
        a0.u4 = *(const uint4*)&A32[(size_t)mr0 * 224 + kc * 16 + quad * 4];
        a1.u4 = *(const uint4*)&A32[(size_t)mr1 * 224 + kc * 16 + quad * 4];
        #pragma unroll
        for (int ni = 0; ni < 4; ++ni) {
            FragU bf;
            bf.u4 = *(const uint4*)&Bt[(size_t)(half * 64 + ni * 16 + m16) * 224 + kc * 16 + quad * 4];
            acc[0][ni] = __builtin_amdgcn_mfma_f32_16x16x32_bf16(a0.f, bf.f, acc[0][ni], 0, 0, 0);
            acc[1][ni] = __builtin_amdgcn_mfma_f32_16x16x32_bf16(a1.f, bf.f, acc[1][ni], 0, 0, 0);
        }
    }
    #pragma unroll
    for (int j = 0; j < 2; ++j) {
        int mrow0 = nb + (wave * 2 + j) * 16;
        #pragma unroll
        for (int ni = 0; ni < 4; ++ni)
            #pragma unroll
            for (int r = 0; r < 4; ++r) {
                int row = mrow0 + quad * 4 + r;
                int col = half * 64 + ni * 16 + m16;
                out[(size_t)row * D + col] = tanhf(acc[j][ni][r]);
            }
    }
}

// ===========================================================================
// Persistent mega kernel with homemade barriers (no cg::grid.sync).
// ===========================================================================
__global__ __launch_bounds__(256) void mega2_kernel(
    const float* __restrict__ user, const float* __restrict__ item,
    const float* __restrict__ Wu, const float* __restrict__ Wi,
    const float* __restrict__ gu, const float* __restrict__ gi,
    const float* __restrict__ uu, const float* __restrict__ ui,
    const float* __restrict__ ue, const float* __restrict__ ie,
    const float* __restrict__ uek, const float* __restrict__ iek,
    const int* __restrict__ unbr, const int* __restrict__ untime,
    const int* __restrict__ inbr, const int* __restrict__ intime,
    float* __restrict__ eproj, unsigned* __restrict__ h32,
    unsigned* __restrict__ A32,
    unsigned* __restrict__ Btu32, unsigned* __restrict__ Bti32,
    unsigned* __restrict__ Bptu32, unsigned* __restrict__ Bpti32,
    unsigned* __restrict__ barriers,
    float* __restrict__ out, int NU, int NI)
{
    __shared__ SharedAll sm;
    int t = threadIdx.x;
    int N = NU + NI;

    for (int b = blockIdx.x; b < 614; b += gridDim.x)
        prep_body(b, t, Wu, Wi, ue, ie, gu, gi, uu, ui, uek, iek,
                  Bptu32, Bpti32, Btu32, Bti32, sm.prep.T);
    grid_barrier(barriers, 0);

    for (int w = blockIdx.x; w < N / 16; w += gridDim.x)
        proj_body(w, t, user, item, Bptu32, Bpti32, h32, eproj, A32, NU);
    grid_barrier(barriers, 1);

    for (int w = blockIdx.x; w < N / 2; w += gridDim.x)
        agg_body(w, t, sm.agg, h32, eproj, unbr, untime, inbr, intime, A32, NU);
    grid_barrier(barriers, 2);

    for (int w = blockIdx.x; w < N / 64; w += gridDim.x)
        gemm_body(w, t, A32, Btu32, Bti32, out, NU);
}

// ===========================================================================
// Fallback kernels (proven R8 pipeline via the same bodies).
// ===========================================================================
__global__ __launch_bounds__(256) void prep_k(
    const float* Wu, const float* Wi, const float* ue, const float* ie,
    const float* gu, const float* gi, const float* uu, const float* ui,
    const float* uek, const float* iek,
    unsigned* Bptu32, unsigned* Bpti32, unsigned* Btu32, unsigned* Bti32)
{
    __shared__ float T[2][128];
    prep_body(blockIdx.x, threadIdx.x, Wu, Wi, ue, ie, gu, gi, uu, ui,
              uek, iek, Bptu32, Bpti32, Btu32, Bti32, T);
}

__global__ __launch_bounds__(256) void proj_k(
    const float* user, const float* item,
    const unsigned* Bptu32, const unsigned* Bpti32,
    unsigned* h32, float* eproj, unsigned* A32, int NU)
{
    proj_body(blockIdx.x, threadIdx.x, user, item, Bptu32, Bpti32,
              h32, eproj, A32, NU);
}

__global__ __launch_bounds__(256) void agg_k(
    const unsigned* h32, const float* eproj,
    const int* unbr, const int* untime, const int* inbr, const int* intime,
    unsigned* A32, int NU)
{
    __shared__ AggShared sh;
    agg_body(blockIdx.x, threadIdx.x, sh, h32, eproj, unbr, untime,
             inbr, intime, A32, NU);
}

__global__ __launch_bounds__(256) void gemm_k(
    const unsigned* A32, const unsigned* Btu32, const unsigned* Bti32,
    float* out, int NU)
{
    gemm_body(blockIdx.x, threadIdx.x, A32, Btu32, Bti32, out, NU);
}

// ===========================================================================
extern "C" void kernel_launch(void* const* d_in, const int* in_sizes, int n_in,
                              void* d_out, int out_size, void* d_ws, size_t ws_size,
                              hipStream_t stream) {
    const float* user   = (const float*)d_in[0];
    const float* item   = (const float*)d_in[1];
    const float* Wu     = (const float*)d_in[2];
    const float* Wi     = (const float*)d_in[3];
    const float* gate_u = (const float*)d_in[4];
    const float* gate_i = (const float*)d_in[5];
    const float* upd_u  = (const float*)d_in[6];
    const float* upd_i  = (const float*)d_in[7];
    const float* uemb   = (const float*)d_in[8];
    const float* uembk  = (const float*)d_in[9];
    const float* iemb   = (const float*)d_in[10];
    const float* iembk  = (const float*)d_in[11];
    const int*   unbr   = (const int*)d_in[12];
    const int*   untime = (const int*)d_in[13];
    const int*   inbr   = (const int*)d_in[14];
    const int*   intime = (const int*)d_in[15];

    int NU = in_sizes[0] / D;
    int NI = in_sizes[1] / D;
    int N  = NU + NI;

    float* eproj  = (float*)d_ws;                   // N*50 f32
    unsigned* h32   = (unsigned*)(eproj + (size_t)N * L);  // N*64 u32
    unsigned* A32   = h32 + (size_t)N * 64;         // N*224 u32
    unsigned* Btu32 = A32 + (size_t)N * 224;        // 128*224 u32 each
    unsigned* Bti32 = Btu32 + 128 * 224;
    unsigned* Bptu32 = Bti32 + 128 * 224;           // 192*64 u32 each
    unsigned* Bpti32 = Bptu32 + 192 * 64;
    unsigned* barriers = Bpti32 + 192 * 64;         // 64 u32 (4 x 16-stride)
    float* out = (float*)d_out;

    // --- persistent attempt: runtime-validated co-residency ---------------
    int numCU = 0, maxBlk = 0, dev = 0;
    (void)hipGetDevice(&dev);
    (void)hipDeviceGetAttribute(&numCU, hipDeviceAttributeMultiprocessorCount, dev);
    (void)hipOccupancyMaxActiveBlocksPerMultiprocessor(
        &maxBlk, (const void*)mega2_kernel, 256, 0);
    int nblk = (maxBlk > 0 && numCU > 0) ? maxBlk * numCU : 0;
    if (nblk > 1024) nblk = 1024;

    if (nblk >= 256) {
        hipMemsetAsync(barriers, 0, 64 * sizeof(unsigned), stream);
        mega2_kernel<<<nblk, 256, 0, stream>>>(
            user, item, Wu, Wi, gate_u, gate_i, upd_u, upd_i,
            uemb, iemb, uembk, iembk, unbr, untime, inbr, intime,
            eproj, h32, A32, Btu32, Bti32, Bptu32, Bpti32,
            barriers, out, NU, NI);
    } else {
        prep_k<<<614, 256, 0, stream>>>(Wu, Wi, uemb, iemb, gate_u, gate_i,
                                        upd_u, upd_i, uembk, iembk,
                                        Bptu32, Bpti32, Btu32, Bti32);
        proj_k<<<N / 16, 256, 0, stream>>>(user, item, Bptu32, Bpti32,
                                           h32, eproj, A32, NU);
        agg_k<<<N / 2, 256, 0, stream>>>(h32, eproj, unbr, untime, inbr,
                                         intime, A32, NU);
        gemm_k<<<N / 64, 256, 0, stream>>>(A32, Btu32, Bti32, out, NU);
    }
}

// Round 12
// 272.337 us; speedup vs baseline: 2.2714x; 1.9939x over previous
//
#include <hip/hip_runtime.h>
#include <math.h>

#define D 128
#define L 50
#define SCALE 0.08838834764831845f   // 1/sqrt(128)

using bf16x8 = __attribute__((ext_vector_type(8))) short;   // MFMA A/B frag
using f32x4  = __attribute__((ext_vector_type(4))) float;   // MFMA C/D frag

union FragU { bf16x8 f; uint2 u2[2]; uint4 u4; };

__device__ __forceinline__ unsigned f2bf(float x) {
    union { float f; unsigned u; } v; v.f = x;
    return (v.u + 0x7fffu + ((v.u >> 16) & 1u)) >> 16;
}
__device__ __forceinline__ float bflo(unsigned u) {
    union { unsigned u; float f; } v; v.u = u << 16; return v.f;
}
__device__ __forceinline__ float bfhi(unsigned u) {
    union { unsigned u; float f; } v; v.u = u & 0xffff0000u; return v.f;
}

struct AggShared {
    unsigned smail[2][L * 66];
    unsigned shb[2][64];
    float se2[2][2][64];
    float salpha[2][L], salpha1[2][L];
    int stime[2][L], sreorder[2][L], snbr[2][L], slast[2];
};

// ===========================================================================
// prep body: b is the ORIGINAL R8 prep block id (0..613).
//  0..49    WE -> Bpt rows 128..177     [prepA]
//  50..305  GU -> B448t cols 0..255     [prepB]
//  306..433 upd_bot -> cols 320..447 + zero 306..319  [prepB]
//  434..561 W^T -> Bpt rows 0..127      [prepA]
//  562..563 zero Bpt rows 178..191      [prepA]
//  564..613 EKGU -> B448t cols 256..305 [prepB, uses LDS T]
// ===========================================================================
__device__ __forceinline__ void prep_body(
    int b, int t,
    const float* Wu, const float* Wi, const float* ue, const float* ie,
    const float* gu, const float* gi, const float* uu, const float* ui,
    const float* uek, const float* iek,
    unsigned* Bptu32, unsigned* Bpti32, unsigned* Btu32, unsigned* Bti32,
    float T[2][128])
{
    if (b < 50) {
        int side = b / 25;
        int o = (b % 25) * 256 + t;
        int d = o / L, l = o % L;
        const float* W = side ? Wi : Wu;
        const float* E = side ? ie : ue;
        unsigned short* Bpt = (unsigned short*)(side ? Bpti32 : Bptu32);
        float a = 0.f;
        for (int k = 0; k < D; ++k) a += W[d * D + k] * E[l * D + k];
        Bpt[(128 + l) * 128 + d] = (unsigned short)f2bf(a);
    } else if (b < 306) {
        int bb = b - 50;
        int side = bb / 128;
        int o = (bb % 128) * 256 + t;
        int r = o >> 7, c = o & 127;                // r 0..255 (GU rows)
        const float* G = side ? gi : gu;
        const float* U = side ? ui : uu;
        unsigned short* Bt = (unsigned short*)(side ? Bti32 : Btu32);
        float a = 0.f;
        for (int k = 0; k < D; ++k) a += G[r * D + k] * U[k * D + c];
        Bt[c * 448 + r] = (unsigned short)f2bf(a);
    } else if (b < 434) {
        int bb = b - 306;
        int side = bb >> 6;
        int o = (bb & 63) * 256 + t;
        int r = o >> 7, c = o & 127;                // r 0..127 (upd_bot)
        const float* U = side ? ui : uu;
        unsigned short* Bt = (unsigned short*)(side ? Bti32 : Btu32);
        Bt[c * 448 + 320 + r] = (unsigned short)f2bf(U[(128 + r) * D + c]);
        if (r < 14) Bt[c * 448 + 306 + r] = 0;
    } else if (b < 562) {
        int bb = b - 434;
        int side = bb >> 6;
        int o = (bb & 63) * 256 + t;
        int k = o >> 7, c = o & 127;
        const float* W = side ? Wi : Wu;
        unsigned short* Bpt = (unsigned short*)(side ? Bpti32 : Bptu32);
        Bpt[c * 128 + k] = (unsigned short)f2bf(W[k * D + c]);
    } else if (b < 564) {
        int side = b - 562;
        unsigned short* Bpt = (unsigned short*)(side ? Bpti32 : Bptu32);
        for (int j = 0; j < 7; ++j)
            Bpt[178 * 128 + t * 7 + j] = 0;
    } else {
        int bb = b - 564;
        int side = bb / 25;
        int ro = (bb % 25) * 2;
        const float* EK = side ? iek : uek;
        const float* G  = side ? gi : gu;
        const float* U  = side ? ui : uu;
        unsigned short* Bt = (unsigned short*)(side ? Bti32 : Btu32);
        int r = t >> 7, c = t & 127;
        float a = 0.f;
        for (int k = 0; k < D; ++k) a += EK[(ro + r) * D + k] * G[k * D + c];
        T[r][c] = a;
        __syncthreads();
        float e = 0.f;
        for (int j = 0; j < D; ++j) e += T[r][j] * U[j * D + c];
        Bt[c * 448 + 256 + ro + r] = (unsigned short)f2bf(e);
        __syncthreads();
    }
}

__device__ __forceinline__ void proj_body(
    int w, int t, const float* user, const float* item,
    const unsigned* Bptu32, const unsigned* Bpti32,
    unsigned* h32, float* eproj, unsigned* A32, int NU)
{
    int wave = t >> 6, lane = t & 63;
    int m16 = lane & 15, quad = lane >> 4;
    int nb = w * 16;
    const float* X = (nb < NU) ? user : item;
    int xoff = (nb < NU) ? 0 : NU;
    const unsigned* Bt = (nb < NU) ? Bptu32 : Bpti32;   // [192][64 u32]

    f32x4 acc[3] = {{0.f,0.f,0.f,0.f},{0.f,0.f,0.f,0.f},{0.f,0.f,0.f,0.f}};
    #pragma unroll
    for (int kc = 0; kc < 4; ++kc) {
        int row = nb + m16;
        const float* src = &X[(size_t)(row - xoff) * D + kc * 32 + quad * 8];
        float4 v0 = *(const float4*)&src[0];
        float4 v1 = *(const float4*)&src[4];
        FragU a;
        a.u4.x = f2bf(v0.x) | (f2bf(v0.y) << 16);
        a.u4.y = f2bf(v0.z) | (f2bf(v0.w) << 16);
        a.u4.z = f2bf(v1.x) | (f2bf(v1.y) << 16);
        a.u4.w = f2bf(v1.z) | (f2bf(v1.w) << 16);
        if (wave == 0)
            *(uint4*)&A32[(size_t)row * 224 + 160 + kc * 16 + quad * 4] = a.u4;
        #pragma unroll
        for (int ni = 0; ni < 3; ++ni) {
            int c = wave * 48 + ni * 16 + m16;
            FragU bb;
            bb.u4 = *(const uint4*)&Bt[(size_t)c * 64 + kc * 16 + quad * 4];
            acc[ni] = __builtin_amdgcn_mfma_f32_16x16x32_bf16(a.f, bb.f, acc[ni], 0, 0, 0);
        }
    }
    #pragma unroll
    for (int ni = 0; ni < 3; ++ni) {
        int col = wave * 48 + ni * 16 + m16;
        #pragma unroll
        for (int r = 0; r < 4; ++r) {
            float me = acc[ni][r];
            float pr = __shfl_xor(me, 1);
            int row = nb + quad * 4 + r;
            if (col < 128) {
                if (!(lane & 1))
                    h32[(size_t)row * 64 + (col >> 1)] = f2bf(me) | (f2bf(pr) << 16);
            } else if (col < 178) {
                eproj[(size_t)row * L + (col - 128)] = me;
            }
        }
    }
}

__device__ __forceinline__ void agg_body(
    int w, int tb, AggShared& sh,
    const unsigned* h32, const float* eproj,
    const int* unbr, const int* untime, const int* inbr, const int* intime,
    unsigned* A32, int NU)
{
    int sub = tb >> 7;
    int ta = tb & 127;
    int awave = ta >> 6, alane = ta & 63;
    int am16 = alane & 15, aquad = alane >> 4;
    int g = w * 2 + sub;

    const unsigned* mail; const int* nbrp; const int* timp;
    if (g < NU) { mail = h32 + (size_t)NU * 64; nbrp = unbr + (size_t)g * L;        timp = untime + (size_t)g * L; }
    else        { mail = h32;                   nbrp = inbr + (size_t)(g - NU) * L; timp = intime + (size_t)(g - NU) * L; }

    if (ta < 64) sh.shb[sub][ta] = h32[(size_t)g * 64 + ta];
    if (ta < L) { sh.stime[sub][ta] = timp[ta]; sh.snbr[sub][ta] = nbrp[ta]; }
    __syncthreads();

    if (ta < L) {
        int ti = sh.stime[sub][ta]; int rank = 0; bool firstmax = true;
        for (int j = 0; j < L; ++j) {
            int tj = sh.stime[sub][j];
            rank += (tj < ti) || (tj == ti && j < ta);
            firstmax = firstmax && ((tj < ti) || (tj == ti && j >= ta));
        }
        sh.sreorder[sub][ta] = L - 1 - rank;
        if (firstmax) sh.slast[sub] = ta;
    }
    {
        int q = ta >> 5, p = ta & 31;
        #pragma unroll
        for (int i = 0; i < 13; ++i) {
            int l = i * 4 + q;
            if (l < L) {
                uint2 v = *(const uint2*)&mail[(size_t)sh.snbr[sub][l] * 64 + p * 2];
                *(uint2*)&sh.smail[sub][l * 66 + 2 * p] = v;
            }
        }
    }
    __syncthreads();

    {
        const unsigned* bptr = (am16 == 1) ? &sh.smail[sub][sh.slast[sub] * 66]
                                           : &sh.shb[sub][0];
        int s0 = awave * 32 + am16;       if (s0 > 49) s0 = 49;
        int s1 = awave * 32 + 16 + am16;  if (s1 > 49) s1 = 49;
        const unsigned* a0p = &sh.smail[sub][s0 * 66];
        const unsigned* a1p = &sh.smail[sub][s1 * 66];
        f32x4 d0 = {0.f, 0.f, 0.f, 0.f}, d1 = {0.f, 0.f, 0.f, 0.f};
        #pragma unroll
        for (int kc = 0; kc < 4; ++kc) {
            int off = kc * 16 + aquad * 4;
            FragU bf_, af0, af1;
            bf_.u2[0] = *(const uint2*)&bptr[off];
            bf_.u2[1] = *(const uint2*)&bptr[off + 2];
            af0.u2[0] = *(const uint2*)&a0p[off];
            af0.u2[1] = *(const uint2*)&a0p[off + 2];
            af1.u2[0] = *(const uint2*)&a1p[off];
            af1.u2[1] = *(const uint2*)&a1p[off + 2];
            d0 = __builtin_amdgcn_mfma_f32_16x16x32_bf16(af0.f, bf_.f, d0, 0, 0, 0);
            d1 = __builtin_amdgcn_mfma_f32_16x16x32_bf16(af1.f, bf_.f, d1, 0, 0, 0);
        }
        if (am16 < 2) {
            #pragma unroll
            for (int r = 0; r < 4; ++r) {
                sh.se2[sub][am16][awave * 32 + aquad * 4 + r]      = d0[r];
                sh.se2[sub][am16][awave * 32 + 16 + aquad * 4 + r] = d1[r];
            }
        }
    }
    __syncthreads();

    float sc = -1e30f;
    if (alane < L) {
        sc = (awave == 0)
           ? (sh.se2[sub][0][alane] + eproj[(size_t)g * L + sh.sreorder[sub][alane]]) * SCALE
           : sh.se2[sub][1][alane] * SCALE;
    }
    float mx = sc;
    for (int off = 32; off; off >>= 1) mx = fmaxf(mx, __shfl_xor(mx, off));
    float ex = (alane < L) ? expf(sc - mx) : 0.f;
    float smv = ex;
    for (int off = 32; off; off >>= 1) smv += __shfl_xor(smv, off);
    float al = ex / smv;
    if (alane < L) {
        if (awave == 0) sh.salpha[sub][alane] = al;
        else            sh.salpha1[sub][alane] = al;
    }
    __syncthreads();

    {
        const float* alp = awave ? sh.salpha1[sub] : sh.salpha[sub];
        const unsigned* base = &sh.smail[sub][alane];
        float ax = 0.f, ay = 0.f;
        for (int l = 0; l < L; ++l) {
            unsigned u = base[l * 66];
            float a = alp[l];
            ax += a * bflo(u);
            ay += a * bfhi(u);
        }
        A32[(size_t)g * 224 + awave * 64 + alane] = f2bf(ax) | (f2bf(ay) << 16);
    }
    if (ta >= 64 && ta < 96) A32[(size_t)g * 224 + 128 + (ta - 64)] = 0u;
    __syncthreads();
    if (ta < L) {
        ((unsigned short*)A32)[(size_t)g * 448 + 256 + sh.sreorder[sub][ta]] =
            (unsigned short)f2bf(sh.salpha[sub][ta]);
    }
    __syncthreads();
}

// ===========================================================================
// k1: prepA — Bpt parts only (WE, W^T, zeros). 180 blocks.
// ===========================================================================
__global__ __launch_bounds__(256) void prepA_k(
    const float* Wu, const float* Wi, const float* ue, const float* ie,
    const float* gu, const float* gi, const float* uu, const float* ui,
    const float* uek, const float* iek,
    unsigned* Bptu32, unsigned* Bpti32, unsigned* Btu32, unsigned* Bti32)
{
    __shared__ float T[2][128];
    int b = blockIdx.x;
    int borig = (b < 50) ? b : b + 384;          // 50..179 -> 434..563
    prep_body(borig, threadIdx.x, Wu, Wi, ue, ie, gu, gi, uu, ui,
              uek, iek, Bptu32, Bpti32, Btu32, Bti32, T);
}

// ===========================================================================
// k2: proj (blocks 0..N/16-1) ∥ prepB (blocks N/16..N/16+433) — independent.
// ===========================================================================
__global__ __launch_bounds__(256) void proj_prepB_k(
    const float* user, const float* item,
    const float* Wu, const float* Wi, const float* ue, const float* ie,
    const float* gu, const float* gi, const float* uu, const float* ui,
    const float* uek, const float* iek,
    const unsigned* Bptu32, const unsigned* Bpti32,
    unsigned* h32, float* eproj, unsigned* A32,
    unsigned* Btu32, unsigned* Bti32, int NU, int nproj)
{
    __shared__ float T[2][128];
    int b = blockIdx.x;
    if (b < nproj) {
        proj_body(b, threadIdx.x, user, item, Bptu32, Bpti32,
                  h32, eproj, A32, NU);
    } else {
        int bb = b - nproj;                      // 0..433
        int borig = (bb < 384) ? bb + 50 : bb - 384 + 564;
        prep_body(borig, threadIdx.x, Wu, Wi, ue, ie, gu, gi, uu, ui,
                  uek, iek, (unsigned*)Bptu32, (unsigned*)Bpti32,
                  Btu32, Bti32, T);
    }
}

// ===========================================================================
// k3: agg+gemm fused. Block owns 16 nodes: 8 agg pair-works, then the
// 16-row x 128-col K=448 gemm for exactly those nodes (A32 hot in L1).
// ===========================================================================
__global__ __launch_bounds__(256) void agg_gemm_k(
    const unsigned* __restrict__ h32, const float* __restrict__ eproj,
    const int* __restrict__ unbr, const int* __restrict__ untime,
    const int* __restrict__ inbr, const int* __restrict__ intime,
    unsigned* __restrict__ A32,
    const unsigned* __restrict__ Btu32, const unsigned* __restrict__ Bti32,
    float* __restrict__ out, int NU)
{
    __shared__ AggShared sh;
    int t = threadIdx.x;
    int nb = blockIdx.x * 16;

    #pragma unroll 1
    for (int i = 0; i < 8; ++i)
        agg_body(blockIdx.x * 8 + i, t, sh, h32, eproj,
                 unbr, untime, inbr, intime, A32, NU);

    __threadfence_block();
    __syncthreads();

    // gemm: out[nb..nb+15][0..127] = tanh(A[16x448] @ B448t^T)
    int wave = t >> 6, lane = t & 63;
    int m16 = lane & 15, quad = lane >> 4;
    const unsigned* Bt = (nb < NU) ? Btu32 : Bti32;     // [128 n][224 u32]
    int mr = nb + m16;

    f32x4 acc[2] = {{0.f, 0.f, 0.f, 0.f}, {0.f, 0.f, 0.f, 0.f}};
    for (int kc = 0; kc < 14; ++kc) {
        FragU a;
        a.u4 = *(const uint4*)&A32[(size_t)mr * 224 + kc * 16 + quad * 4];
        #pragma unroll
        for (int ni = 0; ni < 2; ++ni) {
            int col = wave * 32 + ni * 16 + m16;
            FragU bf;
            bf.u4 = *(const uint4*)&Bt[(size_t)col * 224 + kc * 16 + quad * 4];
            acc[ni] = __builtin_amdgcn_mfma_f32_16x16x32_bf16(a.f, bf.f, acc[ni], 0, 0, 0);
        }
    }
    #pragma unroll
    for (int ni = 0; ni < 2; ++ni)
        #pragma unroll
        for (int r = 0; r < 4; ++r) {
            int row = nb + quad * 4 + r;
            int col = wave * 32 + ni * 16 + m16;
            out[(size_t)row * D + col] = tanhf(acc[ni][r]);
        }
}

// ===========================================================================
extern "C" void kernel_launch(void* const* d_in, const int* in_sizes, int n_in,
                              void* d_out, int out_size, void* d_ws, size_t ws_size,
                              hipStream_t stream) {
    const float* user   = (const float*)d_in[0];
    const float* item   = (const float*)d_in[1];
    const float* Wu     = (const float*)d_in[2];
    const float* Wi     = (const float*)d_in[3];
    const float* gate_u = (const float*)d_in[4];
    const float* gate_i = (const float*)d_in[5];
    const float* upd_u  = (const float*)d_in[6];
    const float* upd_i  = (const float*)d_in[7];
    const float* uemb   = (const float*)d_in[8];
    const float* uembk  = (const float*)d_in[9];
    const float* iemb   = (const float*)d_in[10];
    const float* iembk  = (const float*)d_in[11];
    const int*   unbr   = (const int*)d_in[12];
    const int*   untime = (const int*)d_in[13];
    const int*   inbr   = (const int*)d_in[14];
    const int*   intime = (const int*)d_in[15];

    int NU = in_sizes[0] / D;
    int NI = in_sizes[1] / D;
    int N  = NU + NI;
    int nproj = N / 16;

    float* eproj  = (float*)d_ws;                   // N*50 f32
    unsigned* h32   = (unsigned*)(eproj + (size_t)N * L);  // N*64 u32
    unsigned* A32   = h32 + (size_t)N * 64;         // N*224 u32
    unsigned* Btu32 = A32 + (size_t)N * 224;        // 128*224 u32 each
    unsigned* Bti32 = Btu32 + 128 * 224;
    unsigned* Bptu32 = Bti32 + 128 * 224;           // 192*64 u32 each
    unsigned* Bpti32 = Bptu32 + 192 * 64;
    float* out = (float*)d_out;

    prepA_k<<<180, 256, 0, stream>>>(Wu, Wi, uemb, iemb, gate_u, gate_i,
                                     upd_u, upd_i, uembk, iembk,
                                     Bptu32, Bpti32, Btu32, Bti32);
    proj_prepB_k<<<nproj + 434, 256, 0, stream>>>(
        user, item, Wu, Wi, uemb, iemb, gate_u, gate_i, upd_u, upd_i,
        uembk, iembk, Bptu32, Bpti32, h32, eproj, A32, Btu32, Bti32,
        NU, nproj);
    agg_gemm_k<<<N / 16, 256, 0, stream>>>(h32, eproj, unbr, untime,
                                           inbr, intime, A32,
                                           Btu32, Bti32, out, NU);
}

// Round 13
// 177.770 us; speedup vs baseline: 3.4798x; 1.5320x over previous
//
#include <hip/hip_runtime.h>
#include <math.h>

#define D 128
#define L 50
#define SCALE 0.08838834764831845f   // 1/sqrt(128)

using bf16x8 = __attribute__((ext_vector_type(8))) short;   // MFMA A/B frag
using f32x4  = __attribute__((ext_vector_type(4))) float;   // MFMA C/D frag

union FragU { bf16x8 f; uint2 u2[2]; uint4 u4; };

__device__ __forceinline__ unsigned f2bf(float x) {
    union { float f; unsigned u; } v; v.f = x;
    return (v.u + 0x7fffu + ((v.u >> 16) & 1u)) >> 16;
}
__device__ __forceinline__ float bflo(unsigned u) {
    union { unsigned u; float f; } v; v.u = u << 16; return v.f;
}
__device__ __forceinline__ float bfhi(unsigned u) {
    union { unsigned u; float f; } v; v.u = u & 0xffff0000u; return v.f;
}

// ===========================================================================
// prep body (original R8 block ids 0..613):
//  0..49    WE -> Bpt rows 128..177     [prepA]
//  50..305  GU -> B448t cols 0..255     [prepB]
//  306..433 upd_bot -> cols 320..447 + zero 306..319  [prepB]
//  434..561 W^T -> Bpt rows 0..127      [prepA]
//  562..563 zero Bpt rows 178..191      [prepA]
//  564..613 EKGU -> B448t cols 256..305 [prepB, LDS T]
// ===========================================================================
__device__ __forceinline__ void prep_body(
    int b, int t,
    const float* Wu, const float* Wi, const float* ue, const float* ie,
    const float* gu, const float* gi, const float* uu, const float* ui,
    const float* uek, const float* iek,
    unsigned* Bptu32, unsigned* Bpti32, unsigned* Btu32, unsigned* Bti32,
    float T[2][128])
{
    if (b < 50) {
        int side = b / 25;
        int o = (b % 25) * 256 + t;
        int d = o / L, l = o % L;
        const float* W = side ? Wi : Wu;
        const float* E = side ? ie : ue;
        unsigned short* Bpt = (unsigned short*)(side ? Bpti32 : Bptu32);
        float a = 0.f;
        for (int k = 0; k < D; ++k) a += W[d * D + k] * E[l * D + k];
        Bpt[(128 + l) * 128 + d] = (unsigned short)f2bf(a);
    } else if (b < 306) {
        int bb = b - 50;
        int side = bb / 128;
        int o = (bb % 128) * 256 + t;
        int r = o >> 7, c = o & 127;                // r 0..255 (GU rows)
        const float* G = side ? gi : gu;
        const float* U = side ? ui : uu;
        unsigned short* Bt = (unsigned short*)(side ? Bti32 : Btu32);
        float a = 0.f;
        for (int k = 0; k < D; ++k) a += G[r * D + k] * U[k * D + c];
        Bt[c * 448 + r] = (unsigned short)f2bf(a);
    } else if (b < 434) {
        int bb = b - 306;
        int side = bb >> 6;
        int o = (bb & 63) * 256 + t;
        int r = o >> 7, c = o & 127;                // r 0..127 (upd_bot)
        const float* U = side ? ui : uu;
        unsigned short* Bt = (unsigned short*)(side ? Bti32 : Btu32);
        Bt[c * 448 + 320 + r] = (unsigned short)f2bf(U[(128 + r) * D + c]);
        if (r < 14) Bt[c * 448 + 306 + r] = 0;
    } else if (b < 562) {
        int bb = b - 434;
        int side = bb >> 6;
        int o = (bb & 63) * 256 + t;
        int k = o >> 7, c = o & 127;
        const float* W = side ? Wi : Wu;
        unsigned short* Bpt = (unsigned short*)(side ? Bpti32 : Bptu32);
        Bpt[c * 128 + k] = (unsigned short)f2bf(W[k * D + c]);
    } else if (b < 564) {
        int side = b - 562;
        unsigned short* Bpt = (unsigned short*)(side ? Bpti32 : Bptu32);
        for (int j = 0; j < 7; ++j)
            Bpt[178 * 128 + t * 7 + j] = 0;
    } else {
        int bb = b - 564;
        int side = bb / 25;
        int ro = (bb % 25) * 2;
        const float* EK = side ? iek : uek;
        const float* G  = side ? gi : gu;
        const float* U  = side ? ui : uu;
        unsigned short* Bt = (unsigned short*)(side ? Bti32 : Btu32);
        int r = t >> 7, c = t & 127;
        float a = 0.f;
        for (int k = 0; k < D; ++k) a += EK[(ro + r) * D + k] * G[k * D + c];
        T[r][c] = a;
        __syncthreads();
        float e = 0.f;
        for (int j = 0; j < D; ++j) e += T[r][j] * U[j * D + c];
        Bt[c * 448 + 256 + ro + r] = (unsigned short)f2bf(e);
        __syncthreads();
    }
}

// ---------------------------------------------------------------------------
// proj body (R12-verified): 16 rows/work, B-frags straight from L2.
// ---------------------------------------------------------------------------
__device__ __forceinline__ void proj_body(
    int w, int t, const float* user, const float* item,
    const unsigned* Bptu32, const unsigned* Bpti32,
    unsigned* h32, float* eproj, unsigned* A32, int NU)
{
    int wave = t >> 6, lane = t & 63;
    int m16 = lane & 15, quad = lane >> 4;
    int nb = w * 16;
    const float* X = (nb < NU) ? user : item;
    int xoff = (nb < NU) ? 0 : NU;
    const unsigned* Bt = (nb < NU) ? Bptu32 : Bpti32;   // [192][64 u32]

    f32x4 acc[3] = {{0.f,0.f,0.f,0.f},{0.f,0.f,0.f,0.f},{0.f,0.f,0.f,0.f}};
    #pragma unroll
    for (int kc = 0; kc < 4; ++kc) {
        int row = nb + m16;
        const float* src = &X[(size_t)(row - xoff) * D + kc * 32 + quad * 8];
        float4 v0 = *(const float4*)&src[0];
        float4 v1 = *(const float4*)&src[4];
        FragU a;
        a.u4.x = f2bf(v0.x) | (f2bf(v0.y) << 16);
        a.u4.y = f2bf(v0.z) | (f2bf(v0.w) << 16);
        a.u4.z = f2bf(v1.x) | (f2bf(v1.y) << 16);
        a.u4.w = f2bf(v1.z) | (f2bf(v1.w) << 16);
        if (wave == 0)
            *(uint4*)&A32[(size_t)row * 224 + 160 + kc * 16 + quad * 4] = a.u4;
        #pragma unroll
        for (int ni = 0; ni < 3; ++ni) {
            int c = wave * 48 + ni * 16 + m16;
            FragU bb;
            bb.u4 = *(const uint4*)&Bt[(size_t)c * 64 + kc * 16 + quad * 4];
            acc[ni] = __builtin_amdgcn_mfma_f32_16x16x32_bf16(a.f, bb.f, acc[ni], 0, 0, 0);
        }
    }
    #pragma unroll
    for (int ni = 0; ni < 3; ++ni) {
        int col = wave * 48 + ni * 16 + m16;
        #pragma unroll
        for (int r = 0; r < 4; ++r) {
            float me = acc[ni][r];
            float pr = __shfl_xor(me, 1);
            int row = nb + quad * 4 + r;
            if (col < 128) {
                if (!(lane & 1))
                    h32[(size_t)row * 64 + (col >> 1)] = f2bf(me) | (f2bf(pr) << 16);
            } else if (col < 178) {
                eproj[(size_t)row * L + (col - 128)] = me;
            }
        }
    }
}

// ===========================================================================
// k1: prepA — Bpt parts only. 180 blocks.
// ===========================================================================
__global__ __launch_bounds__(256) void prepA_k(
    const float* Wu, const float* Wi, const float* ue, const float* ie,
    const float* gu, const float* gi, const float* uu, const float* ui,
    const float* uek, const float* iek,
    unsigned* Bptu32, unsigned* Bpti32, unsigned* Btu32, unsigned* Bti32)
{
    __shared__ float T[2][128];
    int b = blockIdx.x;
    int borig = (b < 50) ? b : b + 384;          // 50..179 -> 434..563
    prep_body(borig, threadIdx.x, Wu, Wi, ue, ie, gu, gi, uu, ui,
              uek, iek, Bptu32, Bpti32, Btu32, Bti32, T);
}

// ===========================================================================
// k2: proj (blocks 0..nproj-1) ∥ prepB (blocks nproj..nproj+433).
// ===========================================================================
__global__ __launch_bounds__(256) void proj_prepB_k(
    const float* user, const float* item,
    const float* Wu, const float* Wi, const float* ue, const float* ie,
    const float* gu, const float* gi, const float* uu, const float* ui,
    const float* uek, const float* iek,
    const unsigned* Bptu32, const unsigned* Bpti32,
    unsigned* h32, float* eproj, unsigned* A32,
    unsigned* Btu32, unsigned* Bti32, int NU, int nproj)
{
    __shared__ float T[2][128];
    int b = blockIdx.x;
    if (b < nproj) {
        proj_body(b, threadIdx.x, user, item, Bptu32, Bpti32,
                  h32, eproj, A32, NU);
    } else {
        int bb = b - nproj;                      // 0..433
        int borig = (bb < 384) ? bb + 50 : bb - 384 + 564;
        prep_body(borig, threadIdx.x, Wu, Wi, ue, ie, gu, gi, uu, ui,
                  uek, iek, (unsigned*)Bptu32, (unsigned*)Bpti32,
                  Btu32, Bti32, T);
    }
}

// ===========================================================================
// k3: agg — R8 version; A32[128..159] zeroing moved up (drops one barrier).
// ===========================================================================
__global__ __launch_bounds__(256) void agg_k(
    const unsigned* __restrict__ h32, const float* __restrict__ eproj,
    const int* __restrict__ unbr, const int* __restrict__ untime,
    const int* __restrict__ inbr, const int* __restrict__ intime,
    unsigned* __restrict__ A32, int NU)
{
    __shared__ unsigned smail[2][L * 66];
    __shared__ unsigned shb[2][64];
    __shared__ float se2[2][2][64];
    __shared__ float salpha[2][L], salpha1[2][L];
    __shared__ int stime[2][L], sreorder[2][L], snbr[2][L], slast[2];

    int tb = threadIdx.x;
    int sub = tb >> 7;
    int t = tb & 127;
    int g = blockIdx.x * 2 + sub;
    int wave = t >> 6, lane = t & 63;
    int m16 = lane & 15, quad = lane >> 4;

    const unsigned* mail; const int* nbrp; const int* timp;
    if (g < NU) { mail = h32 + (size_t)NU * 64; nbrp = unbr + (size_t)g * L;        timp = untime + (size_t)g * L; }
    else        { mail = h32;                   nbrp = inbr + (size_t)(g - NU) * L; timp = intime + (size_t)(g - NU) * L; }

    if (t < 64) shb[sub][t] = h32[(size_t)g * 64 + t];
    if (t < L) { stime[sub][t] = timp[t]; snbr[sub][t] = nbrp[t]; }
    if (t >= 64 && t < 96) A32[(size_t)g * 224 + 128 + (t - 64)] = 0u;  // moved up
    __syncthreads();

    if (t < L) {
        int ti = stime[sub][t]; int rank = 0; bool firstmax = true;
        for (int j = 0; j < L; ++j) {
            int tj = stime[sub][j];
            rank += (tj < ti) || (tj == ti && j < t);
            firstmax = firstmax && ((tj < ti) || (tj == ti && j >= t));
        }
        sreorder[sub][t] = L - 1 - rank;
        if (firstmax) slast[sub] = t;
    }
    {
        int q = t >> 5, p = t & 31;
        #pragma unroll
        for (int i = 0; i < 13; ++i) {
            int l = i * 4 + q;
            if (l < L) {
                uint2 v = *(const uint2*)&mail[(size_t)snbr[sub][l] * 64 + p * 2];
                *(uint2*)&smail[sub][l * 66 + 2 * p] = v;
            }
        }
    }
    __syncthreads();

    {
        const unsigned* bptr = (m16 == 1) ? &smail[sub][slast[sub] * 66]
                                          : &shb[sub][0];
        int s0 = wave * 32 + m16;       if (s0 > 49) s0 = 49;
        int s1 = wave * 32 + 16 + m16;  if (s1 > 49) s1 = 49;
        const unsigned* a0p = &smail[sub][s0 * 66];
        const unsigned* a1p = &smail[sub][s1 * 66];
        f32x4 d0 = {0.f, 0.f, 0.f, 0.f}, d1 = {0.f, 0.f, 0.f, 0.f};
        #pragma unroll
        for (int kc = 0; kc < 4; ++kc) {
            int off = kc * 16 + quad * 4;
            FragU bf_, af0, af1;
            bf_.u2[0] = *(const uint2*)&bptr[off];
            bf_.u2[1] = *(const uint2*)&bptr[off + 2];
            af0.u2[0] = *(const uint2*)&a0p[off];
            af0.u2[1] = *(const uint2*)&a0p[off + 2];
            af1.u2[0] = *(const uint2*)&a1p[off];
            af1.u2[1] = *(const uint2*)&a1p[off + 2];
            d0 = __builtin_amdgcn_mfma_f32_16x16x32_bf16(af0.f, bf_.f, d0, 0, 0, 0);
            d1 = __builtin_amdgcn_mfma_f32_16x16x32_bf16(af1.f, bf_.f, d1, 0, 0, 0);
        }
        if (m16 < 2) {
            #pragma unroll
            for (int r = 0; r < 4; ++r) {
                se2[sub][m16][wave * 32 + quad * 4 + r]      = d0[r];
                se2[sub][m16][wave * 32 + 16 + quad * 4 + r] = d1[r];
            }
        }
    }
    __syncthreads();

    float sc = -1e30f;
    if (lane < L) {
        sc = (wave == 0)
           ? (se2[sub][0][lane] + eproj[(size_t)g * L + sreorder[sub][lane]]) * SCALE
           : se2[sub][1][lane] * SCALE;
    }
    float mx = sc;
    for (int off = 32; off; off >>= 1) mx = fmaxf(mx, __shfl_xor(mx, off));
    float ex = (lane < L) ? expf(sc - mx) : 0.f;
    float sm = ex;
    for (int off = 32; off; off >>= 1) sm += __shfl_xor(sm, off);
    float al = ex / sm;
    if (lane < L) { if (wave == 0) salpha[sub][lane] = al; else salpha1[sub][lane] = al; }
    __syncthreads();

    {
        const float* alp = wave ? salpha1[sub] : salpha[sub];
        const unsigned* base = &smail[sub][lane];
        float ax = 0.f, ay = 0.f;
        for (int l = 0; l < L; ++l) {
            unsigned u = base[l * 66];
            float a = alp[l];
            ax += a * bflo(u);
            ay += a * bfhi(u);
        }
        A32[(size_t)g * 224 + wave * 64 + lane] = f2bf(ax) | (f2bf(ay) << 16);
    }
    if (t < L) {
        ((unsigned short*)A32)[(size_t)g * 448 + 256 + sreorder[sub][t]] =
            (unsigned short)f2bf(salpha[sub][t]);
    }
}

// ===========================================================================
// k4: gemm — R8 version (whole B col-half in LDS, barrier-free K-loop).
// ===========================================================================
__global__ __launch_bounds__(256) void gemm_k(
    const unsigned* __restrict__ A32,
    const unsigned* __restrict__ Btu32, const unsigned* __restrict__ Bti32,
    float* __restrict__ out, int NU)
{
    __shared__ __align__(16) unsigned Bs[64 * 228];     // 57 KB
    int t = threadIdx.x;
    int rowblk = blockIdx.x >> 1, half = blockIdx.x & 1;
    int nb = rowblk * 128;
    const unsigned* Bt = (nb < NU) ? Btu32 : Bti32;     // [128 n][224 u32]
    int wave = t >> 6, lane = t & 63;
    int m16 = lane & 15, quad = lane >> 4;

    #pragma unroll
    for (int i = 0; i < 14; ++i) {                      // 3584 uint4
        int idx = t + i * 256;
        int n = idx / 56, q = idx - n * 56;
        uint4 v = *(const uint4*)&Bt[(size_t)(half * 64 + n) * 224 + q * 4];
        *(uint4*)&Bs[n * 228 + q * 4] = v;
    }
    __syncthreads();

    #pragma unroll
    for (int j = 0; j < 2; ++j) {
        int mrow0 = nb + (wave * 2 + j) * 16;
        f32x4 acc[4] = {{0.f,0.f,0.f,0.f},{0.f,0.f,0.f,0.f},
                        {0.f,0.f,0.f,0.f},{0.f,0.f,0.f,0.f}};
        for (int kc = 0; kc < 14; ++kc) {
            FragU af;
            af.u4 = *(const uint4*)&A32[(size_t)(mrow0 + m16) * 224 + kc * 16 + quad * 4];
            #pragma unroll
            for (int ni = 0; ni < 4; ++ni) {
                bf16x8 bf = *(const bf16x8*)&Bs[(ni * 16 + m16) * 228 + kc * 16 + quad * 4];
                acc[ni] = __builtin_amdgcn_mfma_f32_16x16x32_bf16(af.f, bf, acc[ni], 0, 0, 0);
            }
        }
        #pragma unroll
        for (int ni = 0; ni < 4; ++ni)
            #pragma unroll
            for (int r = 0; r < 4; ++r) {
                int row = mrow0 + quad * 4 + r;
                int col = half * 64 + ni * 16 + m16;
                out[(size_t)row * D + col] = tanhf(acc[ni][r]);
            }
    }
}

// ===========================================================================
extern "C" void kernel_launch(void* const* d_in, const int* in_sizes, int n_in,
                              void* d_out, int out_size, void* d_ws, size_t ws_size,
                              hipStream_t stream) {
    const float* user   = (const float*)d_in[0];
    const float* item   = (const float*)d_in[1];
    const float* Wu     = (const float*)d_in[2];
    const float* Wi     = (const float*)d_in[3];
    const float* gate_u = (const float*)d_in[4];
    const float* gate_i = (const float*)d_in[5];
    const float* upd_u  = (const float*)d_in[6];
    const float* upd_i  = (const float*)d_in[7];
    const float* uemb   = (const float*)d_in[8];
    const float* uembk  = (const float*)d_in[9];
    const float* iemb   = (const float*)d_in[10];
    const float* iembk  = (const float*)d_in[11];
    const int*   unbr   = (const int*)d_in[12];
    const int*   untime = (const int*)d_in[13];
    const int*   inbr   = (const int*)d_in[14];
    const int*   intime = (const int*)d_in[15];

    int NU = in_sizes[0] / D;
    int NI = in_sizes[1] / D;
    int N  = NU + NI;
    int nproj = N / 16;

    float* eproj  = (float*)d_ws;                   // N*50 f32
    unsigned* h32   = (unsigned*)(eproj + (size_t)N * L);  // N*64 u32
    unsigned* A32   = h32 + (size_t)N * 64;         // N*224 u32
    unsigned* Btu32 = A32 + (size_t)N * 224;        // 128*224 u32 each
    unsigned* Bti32 = Btu32 + 128 * 224;
    unsigned* Bptu32 = Bti32 + 128 * 224;           // 192*64 u32 each
    unsigned* Bpti32 = Bptu32 + 192 * 64;
    float* out = (float*)d_out;

    prepA_k<<<180, 256, 0, stream>>>(Wu, Wi, uemb, iemb, gate_u, gate_i,
                                     upd_u, upd_i, uembk, iembk,
                                     Bptu32, Bpti32, Btu32, Bti32);
    proj_prepB_k<<<nproj + 434, 256, 0, stream>>>(
        user, item, Wu, Wi, uemb, iemb, gate_u, gate_i, upd_u, upd_i,
        uembk, iembk, Bptu32, Bpti32, h32, eproj, A32, Btu32, Bti32,
        NU, nproj);
    agg_k<<<N / 2, 256, 0, stream>>>(h32, eproj, unbr, untime, inbr,
                                     intime, A32, NU);
    gemm_k<<<N / 64, 256, 0, stream>>>(A32, Btu32, Bti32, out, NU);
}